// Round 6
// baseline (448.519 us; speedup 1.0000x reference)
//
#include <hip/hip_runtime.h>
#include <hip/hip_bf16.h>

#define NN 8192
#define KF 512
#define FF 64
#define GAT_ALPHA 0.2f
#define MSHIFT 20.0f          // safe upper bound on max_j e2[j] (pre-scale)
#define LOG2E 1.44269504f

#define JSPLIT 16             // j-range split; grid = 128 row-groups x 16
#define JW (NN / JSPLIT)      // 512 j's per wave
#define KSTEPS (JW / 32)      // 16 k-steps of 32

#define EXP2F(x) __builtin_amdgcn_exp2f(x)

typedef __attribute__((ext_vector_type(8))) __bf16 bf16x8;
typedef __attribute__((ext_vector_type(4))) float f32x4;
typedef __attribute__((ext_vector_type(4))) int   i32x4;

// ---------------------------------------------------------------------------
// Kernel A: h = x@W (fp32), e1/e2 = (h@a1, h@a2) * log2(e),
//           ht = h^T bf16 [64][8192]. 256 blocks x 256 thr, 32 rows/block.
// ---------------------------------------------------------------------------
__global__ __launch_bounds__(256) void gat_linear(
    const float* __restrict__ x, const float* __restrict__ W,
    const float* __restrict__ av, __hip_bfloat16* __restrict__ ht,
    float* __restrict__ e1, float* __restrict__ e2)
{
    __shared__ float xs[32][33];
    __shared__ float Ws[32][64];
    __shared__ float ep[2][32][17];

    const int t  = threadIdx.x;
    const int fq = t & 15;
    const int rq = t >> 4;
    const int i0 = blockIdx.x * 32;

    const int kl = t & 31, r0 = t >> 5;
    const int fw = t & 63, kq = t >> 6;

    float acc[2][4] = {};

    for (int kt = 0; kt < KF; kt += 32) {
        #pragma unroll
        for (int m = 0; m < 4; ++m)
            xs[kl][r0 + 8 * m] = x[(size_t)(i0 + r0 + 8 * m) * KF + kt + kl];
        #pragma unroll
        for (int m = 0; m < 8; ++m)
            Ws[kq + 4 * m][fw] = W[(size_t)(kt + kq + 4 * m) * FF + fw];
        __syncthreads();
        #pragma unroll
        for (int kk = 0; kk < 32; ++kk) {
            float x0 = xs[kk][rq * 2];
            float x1 = xs[kk][rq * 2 + 1];
            f32x4 wv = *(const f32x4*)&Ws[kk][fq * 4];
            #pragma unroll
            for (int v = 0; v < 4; ++v) {
                acc[0][v] += x0 * wv[v];
                acc[1][v] += x1 * wv[v];
            }
        }
        __syncthreads();
    }

    #pragma unroll
    for (int v = 0; v < 4; ++v) {
        int f = fq * 4 + v;
        union { ushort2 q; __hip_bfloat16 h[2]; } pk;
        pk.h[0] = __float2bfloat16(acc[0][v]);
        pk.h[1] = __float2bfloat16(acc[1][v]);
        *(ushort2*)&ht[(size_t)f * NN + i0 + rq * 2] = pk.q;
    }

    f32x4 a1v = *(const f32x4*)&av[fq * 4];
    f32x4 a2v = *(const f32x4*)&av[64 + fq * 4];
    #pragma unroll
    for (int u = 0; u < 2; ++u) {
        float s1 = 0.f, s2 = 0.f;
        #pragma unroll
        for (int v = 0; v < 4; ++v) {
            s1 += acc[u][v] * a1v[v];
            s2 += acc[u][v] * a2v[v];
        }
        ep[0][rq * 2 + u][fq] = s1;
        ep[1][rq * 2 + u][fq] = s2;
    }
    __syncthreads();
    if (t < 32) {
        float s1 = 0.f, s2 = 0.f;
        #pragma unroll
        for (int q = 0; q < 16; ++q) { s1 += ep[0][t][q]; s2 += ep[1][t][q]; }
        e1[i0 + t] = s1 * LOG2E;
        e2[i0 + t] = s2 * LOG2E;
    }
}

// ---------------------------------------------------------------------------
// Kernel B: barrier-free, register-resident. Wave owns 16 rows x 512 j.
// P produced directly in MFMA A-frag regs (A[m=lane&15][k=quad*8+jj]).
// 4 MFMAs/step for h-features + 1 MFMA vs all-ones B for the softmax
// denominator (no per-lane lpart VALU, no shuffles).
// adj: nontemporal int4, depth-3 prefetch (HBM stream). e2/ht: depth-2 (L2).
// lrelu = max(s, alpha*s) with miL folded: t=max(e2+c0, fma(a,e2,c1)).
// ---------------------------------------------------------------------------
__global__ __launch_bounds__(256, 4) void gat_attn(
    const int* __restrict__ adj, const __hip_bfloat16* __restrict__ ht,
    const float* __restrict__ e1, const float* __restrict__ e2,
    float* __restrict__ accs, float* __restrict__ lsums)
{
    const int t     = threadIdx.x;
    const int lane  = t & 63;
    const int wv    = t >> 6;
    const int n16   = lane & 15;
    const int quad  = lane >> 4;
    const int split = blockIdx.x & (JSPLIT - 1);
    const int i0    = (blockIdx.x >> 4) * 64 + wv * 16;
    const int j0    = split * JW;
    const int row   = i0 + n16;

    const float e1L = e1[row];
    float ms = e1L + MSHIFT * LOG2E;
    const float miL = ms > 0.f ? ms : GAT_ALPHA * ms;
    const float c0  = e1L - miL;                 // t0 = e2 + c0
    const float c1  = GAT_ALPHA * e1L - miL;     // t1 = fma(alpha, e2, c1)

    const int*            ap  = adj + (size_t)row * NN + j0 + quad * 8;
    const float*          epx = e2 + j0 + quad * 8;
    const __hip_bfloat16* hp  = ht + (size_t)n16 * NN + j0 + quad * 8;

    i32x4  aA[3][2];
    float4 eA[2][2];
    bf16x8 bA[2][4];
    f32x4 dacc[4] = {{0.f,0.f,0.f,0.f},{0.f,0.f,0.f,0.f},{0.f,0.f,0.f,0.f},{0.f,0.f,0.f,0.f}};
    f32x4 dl = {0.f, 0.f, 0.f, 0.f};

    union { unsigned short s[8]; bf16x8 v; } ones;
    #pragma unroll
    for (int k = 0; k < 8; ++k) ones.s[k] = 0x3F80;   // bf16 1.0

#define LOADA(sl, st)                                                          \
    {                                                                          \
        aA[sl][0] = __builtin_nontemporal_load((const i32x4*)(ap + (st) * 32));\
        aA[sl][1] = __builtin_nontemporal_load((const i32x4*)(ap + (st) * 32 + 4));\
    }
#define LOADE(sl, st)                                                          \
    {                                                                          \
        eA[sl][0] = *(const float4*)(epx + (st) * 32);                         \
        eA[sl][1] = *(const float4*)(epx + (st) * 32 + 4);                     \
    }
#define LOADH(sl, st)                                                          \
    {                                                                          \
        bA[sl][0] = *(const bf16x8*)(hp + (size_t)(st) * 32);                  \
        bA[sl][1] = *(const bf16x8*)(hp + (size_t)16 * NN + (st) * 32);        \
        bA[sl][2] = *(const bf16x8*)(hp + (size_t)32 * NN + (st) * 32);        \
        bA[sl][3] = *(const bf16x8*)(hp + (size_t)48 * NN + (st) * 32);        \
    }

    LOADA(0, 0) LOADA(1, 1) LOADA(2, 2)
    LOADE(0, 0) LOADE(1, 1)
    LOADH(0, 0) LOADH(1, 1)

    #pragma unroll
    for (int st = 0; st < KSTEPS; ++st) {
        const int s3 = st % 3, s2 = st & 1;
        i32x4  a0 = aA[s3][0], a1 = aA[s3][1];
        float4 e0 = eA[s2][0], ev = eA[s2][1];
        bf16x8 b0 = bA[s2][0], b1 = bA[s2][1], b2 = bA[s2][2], b3 = bA[s2][3];

        if (st + 3 < KSTEPS) LOADA(s3, st + 3)
        if (st + 2 < KSTEPS) { LOADE(s2, st + 2) LOADH(s2, st + 2) }

        union { bf16x8 v; __hip_bfloat16 h[8]; } af;
#define PJ(idx, aval, eval)                                                    \
        {                                                                      \
            float t0 = c0 + (eval);                                            \
            float t1 = __builtin_fmaf(GAT_ALPHA, (eval), c1);                  \
            float p_ = EXP2F(fmaxf(t0, t1));                                   \
            af.h[idx] = __float2bfloat16((aval) > 0 ? p_ : 0.f);               \
        }
        PJ(0, a0.x, e0.x) PJ(1, a0.y, e0.y) PJ(2, a0.z, e0.z) PJ(3, a0.w, e0.w)
        PJ(4, a1.x, ev.x) PJ(5, a1.y, ev.y) PJ(6, a1.z, ev.z) PJ(7, a1.w, ev.w)
#undef PJ

        dacc[0] = __builtin_amdgcn_mfma_f32_16x16x32_bf16(af.v, b0, dacc[0], 0, 0, 0);
        dacc[1] = __builtin_amdgcn_mfma_f32_16x16x32_bf16(af.v, b1, dacc[1], 0, 0, 0);
        dacc[2] = __builtin_amdgcn_mfma_f32_16x16x32_bf16(af.v, b2, dacc[2], 0, 0, 0);
        dacc[3] = __builtin_amdgcn_mfma_f32_16x16x32_bf16(af.v, b3, dacc[3], 0, 0, 0);
        dl      = __builtin_amdgcn_mfma_f32_16x16x32_bf16(af.v, ones.v, dl, 0, 0, 0);
    }
#undef LOADA
#undef LOADE
#undef LOADH

    // dl D-tile: every column holds the row-sum; lanes n16==0 cover all 16 rows
    if (n16 == 0) {
        #pragma unroll
        for (int r = 0; r < 4; ++r)
            lsums[(size_t)split * NN + i0 + quad * 4 + r] = dl[r];
    }

    // D layout: col = lane&15 (feature), row = quad*4 + reg (m89-verified)
    float* ab = accs + (size_t)split * NN * FF;
    #pragma unroll
    for (int ft = 0; ft < 4; ++ft)
        #pragma unroll
        for (int r = 0; r < 4; ++r)
            ab[(size_t)(i0 + quad * 4 + r) * FF + ft * 16 + n16] = dacc[ft][r];
}

// ---------------------------------------------------------------------------
// Epilogue: out = elu( (sum_s accs[s]) / (sum_s lsums[s]) )
// ---------------------------------------------------------------------------
__global__ __launch_bounds__(256) void gat_epilogue(
    const float* __restrict__ accs, const float* __restrict__ lsums,
    float* __restrict__ out)
{
    const int idx = (blockIdx.x * 256 + threadIdx.x) * 4;  // 4 consecutive f, same row
    const int row = idx >> 6;

    float l = 0.f;
    #pragma unroll
    for (int s = 0; s < JSPLIT; ++s) l += lsums[(size_t)s * NN + row];

    f32x4 a = {0.f, 0.f, 0.f, 0.f};
    #pragma unroll
    for (int s = 0; s < JSPLIT; ++s) {
        f32x4 v = *(const f32x4*)(accs + (size_t)s * NN * FF + idx);
        a.x += v.x; a.y += v.y; a.z += v.z; a.w += v.w;
    }

    const float li = 1.f / l;
    f32x4 o;
    #pragma unroll
    for (int v = 0; v < 4; ++v) {
        float hv = a[v] * li;
        o[v] = hv > 0.f ? hv : __expf(hv) - 1.f;
    }
    *(f32x4*)(out + idx) = o;
}

extern "C" void kernel_launch(void* const* d_in, const int* in_sizes, int n_in,
                              void* d_out, int out_size, void* d_ws, size_t ws_size,
                              hipStream_t stream) {
    const float* x   = (const float*)d_in[0];
    const int*   adj = (const int*)d_in[1];
    const float* W   = (const float*)d_in[2];
    const float* av  = (const float*)d_in[3];
    float* out = (float*)d_out;

    // ws: ht bf16[64*8192] (1MB) | e1 f32[8192] | e2 f32[8192]
    //     | accs f32[16][8192*64] (32MB) | lsums f32[16][8192] (512KB)
    char* wsb = (char*)d_ws;
    __hip_bfloat16* ht = (__hip_bfloat16*)wsb;
    float* e1    = (float*)(wsb + (1 << 20));
    float* e2    = e1 + NN;
    float* accs  = e2 + NN;
    float* lsums = accs + (size_t)JSPLIT * NN * FF;

    gat_linear<<<256, 256, 0, stream>>>(x, W, av, ht, e1, e2);
    gat_attn<<<(NN / 64) * JSPLIT, 256, 0, stream>>>(adj, ht, e1, e2, accs, lsums);
    gat_epilogue<<<NN * FF / 1024, 256, 0, stream>>>(accs, lsums, out);
}

// Round 7
// 432.183 us; speedup vs baseline: 1.0378x; 1.0378x over previous
//
#include <hip/hip_runtime.h>
#include <hip/hip_bf16.h>

#define NN 8192
#define KF 512
#define FF 64
#define GAT_ALPHA 0.2f
#define MSHIFT 20.0f          // safe upper bound on max_j e2[j] (pre-scale)
#define LOG2E 1.44269504f

#define JSPLIT 16             // j-range split; grid = 128 row-groups x 16
#define JW (NN / JSPLIT)      // 512 j's per wave
#define KSTEPS (JW / 32)      // 16 k-steps of 32

#define EXP2F(x) __builtin_amdgcn_exp2f(x)

typedef __attribute__((ext_vector_type(8))) __bf16 bf16x8;
typedef __attribute__((ext_vector_type(4))) float f32x4;
typedef __attribute__((ext_vector_type(4))) int   i32x4;

// ---------------------------------------------------------------------------
// Kernel A: h = x@W (fp32), e1/e2 = (h@a1, h@a2) * log2(e),
//           ht = h^T bf16 [64][8192]. 256 blocks x 256 thr, 32 rows/block.
// ---------------------------------------------------------------------------
__global__ __launch_bounds__(256) void gat_linear(
    const float* __restrict__ x, const float* __restrict__ W,
    const float* __restrict__ av, __hip_bfloat16* __restrict__ ht,
    float* __restrict__ e1, float* __restrict__ e2)
{
    __shared__ float xs[32][33];
    __shared__ float Ws[32][64];
    __shared__ float ep[2][32][17];

    const int t  = threadIdx.x;
    const int fq = t & 15;
    const int rq = t >> 4;
    const int i0 = blockIdx.x * 32;

    const int kl = t & 31, r0 = t >> 5;
    const int fw = t & 63, kq = t >> 6;

    float acc[2][4] = {};

    for (int kt = 0; kt < KF; kt += 32) {
        #pragma unroll
        for (int m = 0; m < 4; ++m)
            xs[kl][r0 + 8 * m] = x[(size_t)(i0 + r0 + 8 * m) * KF + kt + kl];
        #pragma unroll
        for (int m = 0; m < 8; ++m)
            Ws[kq + 4 * m][fw] = W[(size_t)(kt + kq + 4 * m) * FF + fw];
        __syncthreads();
        #pragma unroll
        for (int kk = 0; kk < 32; ++kk) {
            float x0 = xs[kk][rq * 2];
            float x1 = xs[kk][rq * 2 + 1];
            f32x4 wv = *(const f32x4*)&Ws[kk][fq * 4];
            #pragma unroll
            for (int v = 0; v < 4; ++v) {
                acc[0][v] += x0 * wv[v];
                acc[1][v] += x1 * wv[v];
            }
        }
        __syncthreads();
    }

    #pragma unroll
    for (int v = 0; v < 4; ++v) {
        int f = fq * 4 + v;
        union { ushort2 q; __hip_bfloat16 h[2]; } pk;
        pk.h[0] = __float2bfloat16(acc[0][v]);
        pk.h[1] = __float2bfloat16(acc[1][v]);
        *(ushort2*)&ht[(size_t)f * NN + i0 + rq * 2] = pk.q;
    }

    f32x4 a1v = *(const f32x4*)&av[fq * 4];
    f32x4 a2v = *(const f32x4*)&av[64 + fq * 4];
    #pragma unroll
    for (int u = 0; u < 2; ++u) {
        float s1 = 0.f, s2 = 0.f;
        #pragma unroll
        for (int v = 0; v < 4; ++v) {
            s1 += acc[u][v] * a1v[v];
            s2 += acc[u][v] * a2v[v];
        }
        ep[0][rq * 2 + u][fq] = s1;
        ep[1][rq * 2 + u][fq] = s2;
    }
    __syncthreads();
    if (t < 32) {
        float s1 = 0.f, s2 = 0.f;
        #pragma unroll
        for (int q = 0; q < 16; ++q) { s1 += ep[0][t][q]; s2 += ep[1][t][q]; }
        e1[i0 + t] = s1 * LOG2E;
        e2[i0 + t] = s2 * LOG2E;
    }
}

// ---------------------------------------------------------------------------
// Kernel B: barrier-free, register-resident. Wave owns 16 rows x 512 j.
// P produced directly in MFMA A-frag regs (A[m=lane&15][k=quad*8+jj]).
// 4 MFMAs/step for h-features + 1 MFMA vs all-ones B for the denominator.
// Register budget trimmed under the (256,4) 128-VGPR cap (spill fix):
//   adj depth-2 prefetch (16 regs), e2 depth-2 (16), ht depth-1 (16),
//   dacc 16 + dl 4 + af 4 + ones 4 + addrs/consts ~20  ->  ~110 total.
// ---------------------------------------------------------------------------
__global__ __launch_bounds__(256, 4) void gat_attn(
    const int* __restrict__ adj, const __hip_bfloat16* __restrict__ ht,
    const float* __restrict__ e1, const float* __restrict__ e2,
    float* __restrict__ accs, float* __restrict__ lsums)
{
    const int t     = threadIdx.x;
    const int lane  = t & 63;
    const int wv    = t >> 6;
    const int n16   = lane & 15;
    const int quad  = lane >> 4;
    const int split = blockIdx.x & (JSPLIT - 1);
    const int i0    = (blockIdx.x >> 4) * 64 + wv * 16;
    const int j0    = split * JW;
    const int row   = i0 + n16;

    const float e1L = e1[row];
    float ms = e1L + MSHIFT * LOG2E;
    const float miL = ms > 0.f ? ms : GAT_ALPHA * ms;
    const float c0  = e1L - miL;                 // t0 = e2 + c0
    const float c1  = GAT_ALPHA * e1L - miL;     // t1 = fma(alpha, e2, c1)

    const int*            ap  = adj + (size_t)row * NN + j0 + quad * 8;
    const float*          epx = e2 + j0 + quad * 8;
    const __hip_bfloat16* hp  = ht + (size_t)n16 * NN + j0 + quad * 8;

    i32x4  aA[2][2];
    float4 eA[2][2];
    f32x4 dacc[4] = {{0.f,0.f,0.f,0.f},{0.f,0.f,0.f,0.f},{0.f,0.f,0.f,0.f},{0.f,0.f,0.f,0.f}};
    f32x4 dl = {0.f, 0.f, 0.f, 0.f};

    union { unsigned short s[8]; bf16x8 v; } ones;
    #pragma unroll
    for (int k = 0; k < 8; ++k) ones.s[k] = 0x3F80;   // bf16 1.0

#define LOADA(sl, st)                                                          \
    {                                                                          \
        aA[sl][0] = *(const i32x4*)(ap + (st) * 32);                           \
        aA[sl][1] = *(const i32x4*)(ap + (st) * 32 + 4);                       \
    }
#define LOADE(sl, st)                                                          \
    {                                                                          \
        eA[sl][0] = *(const float4*)(epx + (st) * 32);                         \
        eA[sl][1] = *(const float4*)(epx + (st) * 32 + 4);                     \
    }

    LOADA(0, 0) LOADA(1, 1)
    LOADE(0, 0) LOADE(1, 1)

    #pragma unroll
    for (int st = 0; st < KSTEPS; ++st) {
        const int sl = st & 1;

        // ht fragments: depth-1 (L1/L2-hot), issued first to overlap PJ chain
        bf16x8 b0 = *(const bf16x8*)(hp + (size_t)st * 32);
        bf16x8 b1 = *(const bf16x8*)(hp + (size_t)16 * NN + st * 32);
        bf16x8 b2 = *(const bf16x8*)(hp + (size_t)32 * NN + st * 32);
        bf16x8 b3 = *(const bf16x8*)(hp + (size_t)48 * NN + st * 32);

        // consume-then-overwrite: copy to locals, then issue prefetch
        i32x4  a0 = aA[sl][0], a1 = aA[sl][1];
        float4 e0 = eA[sl][0], ev = eA[sl][1];
        if (st + 2 < KSTEPS) { LOADA(sl, st + 2) LOADE(sl, st + 2) }

        union { bf16x8 v; __hip_bfloat16 h[8]; } af;
#define PJ(idx, aval, eval)                                                    \
        {                                                                      \
            float t0 = c0 + (eval);                                            \
            float t1 = __builtin_fmaf(GAT_ALPHA, (eval), c1);                  \
            float p_ = EXP2F(fmaxf(t0, t1));                                   \
            af.h[idx] = __float2bfloat16((aval) > 0 ? p_ : 0.f);               \
        }
        PJ(0, a0.x, e0.x) PJ(1, a0.y, e0.y) PJ(2, a0.z, e0.z) PJ(3, a0.w, e0.w)
        PJ(4, a1.x, ev.x) PJ(5, a1.y, ev.y) PJ(6, a1.z, ev.z) PJ(7, a1.w, ev.w)
#undef PJ

        dacc[0] = __builtin_amdgcn_mfma_f32_16x16x32_bf16(af.v, b0, dacc[0], 0, 0, 0);
        dacc[1] = __builtin_amdgcn_mfma_f32_16x16x32_bf16(af.v, b1, dacc[1], 0, 0, 0);
        dacc[2] = __builtin_amdgcn_mfma_f32_16x16x32_bf16(af.v, b2, dacc[2], 0, 0, 0);
        dacc[3] = __builtin_amdgcn_mfma_f32_16x16x32_bf16(af.v, b3, dacc[3], 0, 0, 0);
        dl      = __builtin_amdgcn_mfma_f32_16x16x32_bf16(af.v, ones.v, dl, 0, 0, 0);
    }
#undef LOADA
#undef LOADE

    // dl D-tile: every column holds the row-sum; lanes n16==0 cover all 16 rows
    if (n16 == 0) {
        #pragma unroll
        for (int r = 0; r < 4; ++r)
            lsums[(size_t)split * NN + i0 + quad * 4 + r] = dl[r];
    }

    // D layout: col = lane&15 (feature), row = quad*4 + reg (m89-verified)
    float* ab = accs + (size_t)split * NN * FF;
    #pragma unroll
    for (int ft = 0; ft < 4; ++ft)
        #pragma unroll
        for (int r = 0; r < 4; ++r)
            ab[(size_t)(i0 + quad * 4 + r) * FF + ft * 16 + n16] = dacc[ft][r];
}

// ---------------------------------------------------------------------------
// Epilogue: out = elu( (sum_s accs[s]) / (sum_s lsums[s]) )
// ---------------------------------------------------------------------------
__global__ __launch_bounds__(256) void gat_epilogue(
    const float* __restrict__ accs, const float* __restrict__ lsums,
    float* __restrict__ out)
{
    const int idx = (blockIdx.x * 256 + threadIdx.x) * 4;  // 4 consecutive f, same row
    const int row = idx >> 6;

    float l = 0.f;
    #pragma unroll
    for (int s = 0; s < JSPLIT; ++s) l += lsums[(size_t)s * NN + row];

    f32x4 a = {0.f, 0.f, 0.f, 0.f};
    #pragma unroll
    for (int s = 0; s < JSPLIT; ++s) {
        f32x4 v = *(const f32x4*)(accs + (size_t)s * NN * FF + idx);
        a.x += v.x; a.y += v.y; a.z += v.z; a.w += v.w;
    }

    const float li = 1.f / l;
    f32x4 o;
    #pragma unroll
    for (int v = 0; v < 4; ++v) {
        float hv = a[v] * li;
        o[v] = hv > 0.f ? hv : __expf(hv) - 1.f;
    }
    *(f32x4*)(out + idx) = o;
}

extern "C" void kernel_launch(void* const* d_in, const int* in_sizes, int n_in,
                              void* d_out, int out_size, void* d_ws, size_t ws_size,
                              hipStream_t stream) {
    const float* x   = (const float*)d_in[0];
    const int*   adj = (const int*)d_in[1];
    const float* W   = (const float*)d_in[2];
    const float* av  = (const float*)d_in[3];
    float* out = (float*)d_out;

    // ws: ht bf16[64*8192] (1MB) | e1 f32[8192] | e2 f32[8192]
    //     | accs f32[16][8192*64] (32MB) | lsums f32[16][8192] (512KB)
    char* wsb = (char*)d_ws;
    __hip_bfloat16* ht = (__hip_bfloat16*)wsb;
    float* e1    = (float*)(wsb + (1 << 20));
    float* e2    = e1 + NN;
    float* accs  = e2 + NN;
    float* lsums = accs + (size_t)JSPLIT * NN * FF;

    gat_linear<<<256, 256, 0, stream>>>(x, W, av, ht, e1, e2);
    gat_attn<<<(NN / 64) * JSPLIT, 256, 0, stream>>>(adj, ht, e1, e2, accs, lsums);
    gat_epilogue<<<NN * FF / 1024, 256, 0, stream>>>(accs, lsums, out);
}